// Round 8
// baseline (145.849 us; speedup 1.0000x reference)
//
#include <hip/hip_runtime.h>
#include <hip/hip_bf16.h>
#include <stdint.h>

typedef unsigned long long ull;

#define B_   8
#define C_   64
#define H_   128
#define W_   128
#define HW_  (H_*W_)          // 16384
#define NPIX (B_*HW_)         // 131072
#define NELEM (B_*C_*HW_)     // 8388608
#define G1_  4
#define CPG_ 16               // channels per group (conv1)
#define TAU_ 5e-5f            // zero-band half-width for act2 sign decision
#define K3BLK 1024            // blocks for k3 stats (4/CU)

// ---------------- K0: prep (alphas, weight masks, loss) ----------------
__global__ __launch_bounds__(576) void k0_prep(
    const float* __restrict__ w1, const float* __restrict__ w2,
    const float* __restrict__ loss, float* __restrict__ loss_out,
    uint32_t* __restrict__ wmask1, float* __restrict__ alpha1f,
    ull* __restrict__ wpos2, ull* __restrict__ wnz2, double* __restrict__ alpha2)
{
    int t = threadIdx.x;
    if (t == 0) loss_out[0] = loss[0];

    if (t < 64) {
        const float* wo = w1 + t * CPG_ * 9;
        double s = 0.0;
        for (int i = 0; i < CPG_ * 9; i++) s += fabs((double)wo[i]);
        alpha1f[t] = (float)(s / (double)(CPG_ * 9));
    }
    if (t < 64) {
        double s = 0.0; ull pos = 0ull, nz = 0ull;
        for (int i = 0; i < 64; i++) {
            float w = w2[t * 64 + i];
            s += fabs((double)w);
            if (w > 0.f) pos |= (1ull << i);
            if (w != 0.f) nz |= (1ull << i);
        }
        alpha2[t] = s / 64.0;
        wpos2[t] = pos; wnz2[t] = nz;
    }

    // per (o,tap): sign/nz masks over in-channels
    if (t < G1_ * CPG_ * 9) {
        int g   = t / (CPG_ * 9);
        int rem = t % (CPG_ * 9);
        int oc  = rem / 9;
        int tap = rem % 9;
        int o = g * CPG_ + oc;
        uint32_t pos = 0, nz = 0;
        for (int i = 0; i < CPG_; i++) {
            float w = w1[(o * CPG_ + i) * 9 + tap];
            if (w > 0.f) pos |= (1u << i);
            if (w != 0.f) nz |= (1u << i);
        }
        wmask1[t] = (nz << 16) | pos;
    }
}

// ---------------- K1a: per-pixel 64-ch ternary sign pack (one pass over x) ---------
// packed1[p] = 4 group words, each (nz16<<16)|pos16, matching wmask1 bit layout.
__global__ __launch_bounds__(256) void k1a_pack(
    const float* __restrict__ x, const float* __restrict__ b11,
    uint4* __restrict__ packed1)
{
    __shared__ float cB11[64];
    int t = threadIdx.x;
    if (t < 64) cB11[t] = b11[t];
    __syncthreads();
    int p = blockIdx.x * 256 + t;
    if (p >= NPIX) return;
    int b = p >> 14, hw = p & (HW_ - 1);
    const float* xb = x + (size_t)b * C_ * HW_ + hw;
    uint32_t m[4] = {0u, 0u, 0u, 0u};
    #pragma unroll
    for (int c = 0; c < 64; c++) {
        float v = __fadd_rn(xb[c * HW_], cB11[c]);
        uint32_t pbit = 1u << (c & 15);
        uint32_t nbit = 0x10000u << (c & 15);
        if (v > 0.f)      m[c >> 4] |= pbit | nbit;
        else if (v < 0.f) m[c >> 4] |= nbit;
    }
    packed1[p] = make_uint4(m[0], m[1], m[2], m[3]);
}

// ---------------- K1: 3x3 grouped ternary conv (popcount) + PARTIAL stats ----------
// Stages pre-packed act masks (1 dword per halo pixel, L2-resident). Math identical.
__global__ __launch_bounds__(256) void k1_conv1(
    const uint32_t* __restrict__ packed1,   // as 4 words/pixel
    const uint32_t* __restrict__ wmask1,
    int8_t* __restrict__ conv1s,
    int* __restrict__ partS1, int* __restrict__ partQ1)
{
    const int bg = blockIdx.y;          // b*4 + g
    const int b = bg >> 2, g = bg & 3;
    const int ty0 = (blockIdx.x >> 3) * 16;
    const int tx0 = (blockIdx.x & 7) * 16;

    __shared__ uint32_t sAct[18 * 18];
    __shared__ uint32_t sW[CPG_ * 9];
    __shared__ int redS[4][CPG_];
    __shared__ int redQ[4][CPG_];

    int t = threadIdx.x;
    if (t < CPG_ * 9) sW[t] = wmask1[g * (CPG_ * 9) + t];

    for (int p = t; p < 18 * 18; p += 256) {
        int r = p / 18, cc = p % 18;
        int y = ty0 - 1 + r, xx = tx0 - 1 + cc;
        uint32_t m = 0;
        if (y >= 0 && y < H_ && xx >= 0 && xx < W_)
            m = packed1[(size_t)((b << 14) + y * W_ + xx) * 4 + g];
        sAct[p] = m;
    }
    __syncthreads();

    int tyl = t >> 4, txl = t & 15;
    uint32_t a[9];
    #pragma unroll
    for (int dy = 0; dy < 3; dy++)
        #pragma unroll
        for (int dx = 0; dx < 3; dx++)
            a[dy * 3 + dx] = sAct[(tyl + dy) * 18 + (txl + dx)];

    size_t obase = (size_t)(b * C_ + g * CPG_) * HW_ + (ty0 + tyl) * W_ + (tx0 + txl);

    #pragma unroll
    for (int oc = 0; oc < CPG_; oc++) {
        int s = 0;
        #pragma unroll
        for (int tap = 0; tap < 9; tap++) {
            uint32_t wm = sW[oc * 9 + tap];
            uint32_t av = a[tap];
            uint32_t nzb = (wm >> 16) & (av >> 16);
            uint32_t match = (~(wm ^ av)) & nzb;
            s += 2 * __popc(match) - __popc(nzb);
        }
        conv1s[obase + (size_t)oc * HW_] = (int8_t)s;   // |s| <= 144, lossless

        int sr = s, q = s * s;
        for (int off = 32; off > 0; off >>= 1) {
            sr += __shfl_down(sr, off, 64);
            q  += __shfl_down(q, off, 64);
        }
        if ((t & 63) == 0) { redS[t >> 6][oc] = sr; redQ[t >> 6][oc] = q; }
    }
    __syncthreads();
    if (t < CPG_) {
        int bid = blockIdx.y * 64 + blockIdx.x;    // 0..2047
        partS1[bid * CPG_ + t] = redS[0][t] + redS[1][t] + redS[2][t] + redS[3][t];
        partQ1[bid * CPG_ + t] = redQ[0][t] + redQ[1][t] + redQ[2][t] + redQ[3][t];
    }
}

// ---------------- F1: reduce partials -> BN1 channel constants ----------------------
__global__ __launch_bounds__(1024) void f1_bn(
    const float* __restrict__ gamma, const float* __restrict__ beta,
    const float* __restrict__ alpha1f,
    const int* __restrict__ partS1, const int* __restrict__ partQ1,
    float* __restrict__ mu_f, float* __restrict__ inv_f,
    float* __restrict__ sA, float* __restrict__ sh)
{
    __shared__ int rS[16][64];
    __shared__ long long rQ[16][64];
    int tid = threadIdx.x;
    int c = tid & 63, j = tid >> 6;      // 16 threads per channel
    int g = c >> 4, oc = c & 15;
    int s = 0; long long q = 0;
    for (int i = j; i < 512; i += 16) {  // 512 partials per channel (8 b * 64 bx)
        int bb = i >> 6, bx = i & 63;
        int bid = (bb * 4 + g) * 64 + bx;
        s += partS1[bid * CPG_ + oc];
        q += (long long)partQ1[bid * CPG_ + oc];
    }
    rS[j][c] = s; rQ[j][c] = q;
    __syncthreads();
    if (tid < 64) {
        int S = 0; long long Q = 0;
        #pragma unroll
        for (int k = 0; k < 16; k++) { S += rS[k][tid]; Q += rQ[k][tid]; }
        double n = (double)NPIX;
        double a = (double)alpha1f[tid];
        double sm = (double)S / n;
        double qm = (double)Q / n;
        double mu_d = a * sm;
        double var_d = a * a * (qm - sm * sm);
        double inv_d = 1.0 / sqrt(var_d + 1e-5);
        mu_f[tid] = (float)mu_d;
        inv_f[tid] = (float)inv_d;
        double scale = (double)gamma[tid] * inv_d;
        sA[tid] = (float)(scale * a);
        sh[tid] = (float)((double)beta[tid] - scale * mu_d);
    }
}

// ---------------- K2b: out1 recompute (ref op order); pack act2 with ZERO-BAND ------
__global__ __launch_bounds__(256) void k2b_pack(
    const int8_t* __restrict__ conv1s, const float* __restrict__ x,
    const float* __restrict__ alpha1f,
    const float* __restrict__ mu_f, const float* __restrict__ inv_f,
    const float* __restrict__ g1, const float* __restrict__ be1,
    const float* __restrict__ b12, const float* __restrict__ p1, const float* __restrict__ b13,
    const float* __restrict__ b21,
    ulonglong2* __restrict__ packed)
{
    __shared__ float cAf[64], cMu[64], cInv[64], cG[64], cB[64],
                     cB12[64], cP1[64], cB13[64], cB21[64];
    int t = threadIdx.x;
    if (t < 64) {
        cAf[t] = alpha1f[t]; cMu[t] = mu_f[t]; cInv[t] = inv_f[t];
        cG[t] = g1[t]; cB[t] = be1[t];
        cB12[t] = b12[t]; cP1[t] = p1[t]; cB13[t] = b13[t]; cB21[t] = b21[t];
    }
    __syncthreads();

    int p = blockIdx.x * 256 + t;   // 0..131071
    if (p >= NPIX) return;
    int b = p >> 14, hw = p & (HW_ - 1);
    const int8_t* sbase = conv1s + (size_t)b * C_ * HW_ + hw;
    const float*  xbase = x      + (size_t)b * C_ * HW_ + hw;
    ull pos = 0ull, nz = 0ull;
    #pragma unroll 4
    for (int c = 0; c < 64; c++) {
        float cf = (float)((double)cAf[c] * (double)sbase[c * HW_]);
        float v1 = __fsub_rn(cf, cMu[c]);
        float v2 = __fmul_rn(cG[c], v1);
        float v3 = __fmul_rn(v2, cInv[c]);
        float v4 = __fadd_rn(v3, cB[c]);
        float o  = __fadd_rn(v4, xbase[c * HW_]);   // + residual x
        float tt = __fadd_rn(o, cB12[c]);
        float pr = (tt >= 0.f) ? tt : __fmul_rn(cP1[c], tt);
        float o1 = __fadd_rn(pr, cB13[c]);
        float w  = __fadd_rn(o1, cB21[c]);
        if (w > TAU_)          pos |= (1ull << c);
        if (fabsf(w) > TAU_)   nz  |= (1ull << c);
    }
    packed[p] = make_ulonglong2(pos, nz);
}

// ---------------- K3: 1x1 ternary conv integer stats (high-occupancy partials) -----
__global__ __launch_bounds__(256) void k3_stats2(
    const ulonglong2* __restrict__ packed,
    const ull* __restrict__ wpos2, const ull* __restrict__ wnz2,
    int* __restrict__ partS2, int* __restrict__ partQ2)
{
    __shared__ int sS[4][64], sQ[4][64];
    int t = threadIdx.x;
    int lane = t & 63;
    int w = blockIdx.x * 4 + (t >> 6);
    ull wp = wpos2[lane], wn = wnz2[lane];
    int sacc = 0, qacc = 0;
    #pragma unroll 4
    for (int p = w; p < NPIX; p += 4 * K3BLK) {
        ulonglong2 pk = packed[p];
        ull nzb = wn & pk.y;
        ull match = (~(wp ^ pk.x)) & nzb;
        int s = 2 * __popcll(match) - __popcll(nzb);
        sacc += s;
        qacc += s * s;
    }
    sS[t >> 6][lane] = sacc; sQ[t >> 6][lane] = qacc;
    __syncthreads();
    if (t < 64) {
        partS2[blockIdx.x * 64 + t] = sS[0][t] + sS[1][t] + sS[2][t] + sS[3][t];
        partQ2[blockIdx.x * 64 + t] = sQ[0][t] + sQ[1][t] + sQ[2][t] + sQ[3][t];
    }
}

// ---------------- F2: reduce partials -> BN2 folded constants -----------------------
__global__ __launch_bounds__(1024) void f2_bn(
    const float* __restrict__ gamma, const float* __restrict__ beta,
    const double* __restrict__ alpha,
    const int* __restrict__ partS2, const int* __restrict__ partQ2,
    float* __restrict__ sA, float* __restrict__ sh)
{
    __shared__ int rS[16][64];
    __shared__ long long rQ[16][64];
    int tid = threadIdx.x;
    int c = tid & 63, j = tid >> 6;
    int s = 0; long long q = 0;
    for (int i = j; i < K3BLK; i += 16) {
        s += partS2[i * 64 + c];
        q += (long long)partQ2[i * 64 + c];
    }
    rS[j][c] = s; rQ[j][c] = q;
    __syncthreads();
    if (tid < 64) {
        int S = 0; long long Q = 0;
        #pragma unroll
        for (int k = 0; k < 16; k++) { S += rS[k][tid]; Q += rQ[k][tid]; }
        double n = (double)NPIX;
        double a = alpha[tid];
        double sm = (double)S / n;
        double qm = (double)Q / n;
        double var = a * a * (qm - sm * sm);
        double inv = 1.0 / sqrt(var + 1e-5);
        double scale = (double)gamma[tid] * inv;
        sA[tid] = (float)(scale * a);
        sh[tid] = (float)((double)beta[tid] - scale * a * sm);
    }
}

// ---------------- K4: out1 inline + 1x1 conv + BN2 + epilogue -> out ----------------
__global__ __launch_bounds__(256) void k4_out2(
    const ulonglong2* __restrict__ packed,
    const int8_t* __restrict__ conv1s, const float* __restrict__ x,
    const float* __restrict__ sA1, const float* __restrict__ sh1,
    const float* __restrict__ b12, const float* __restrict__ p1, const float* __restrict__ b13,
    const ull* __restrict__ wpos2, const ull* __restrict__ wnz2,
    const float* __restrict__ sA2, const float* __restrict__ sh2,
    const float* __restrict__ b22, const float* __restrict__ p2, const float* __restrict__ b23,
    float* __restrict__ out2)
{
    int i4 = (blockIdx.x * 256 + threadIdx.x) * 4;
    if (i4 >= NELEM) return;
    int c = (i4 >> 14) & 63;
    int b = i4 >> 20;
    int hw = i4 & (HW_ - 1);
    int p = b * HW_ + hw;
    ull wp = wpos2[c], wn = wnz2[c];
    float a1 = sA1[c], s1c = sh1[c], bb1 = b12[c], pp1 = p1[c], b31 = b13[c];
    float a2 = sA2[c], s2c = sh2[c], bb2 = b22[c], pp2 = p2[c], b32 = b23[c];
    char4 sv = *(const char4*)(conv1s + i4);
    float4 xv = *(const float4*)(x + i4);
    float ss[4] = {(float)sv.x, (float)sv.y, (float)sv.z, (float)sv.w};
    float xx[4] = {xv.x, xv.y, xv.z, xv.w};
    float r[4];
    #pragma unroll
    for (int k = 0; k < 4; k++) {
        float v = a1 * ss[k] + s1c + xx[k];
        float t1 = v + bb1;
        float pr1 = t1 >= 0.f ? t1 : pp1 * t1;
        float o1 = pr1 + b31;
        ulonglong2 pk = packed[p + k];
        ull nzb = wn & pk.y;
        ull match = (~(wp ^ pk.x)) & nzb;
        int s = 2 * __popcll(match) - __popcll(nzb);
        float v2 = a2 * (float)s + s2c + o1;
        float t2 = v2 + bb2;
        float pr2 = t2 >= 0.f ? t2 : pp2 * t2;
        r[k] = pr2 + b32;
    }
    *(float4*)(out2 + i4) = make_float4(r[0], r[1], r[2], r[3]);
}

// ---------------- launch ----------------
extern "C" void kernel_launch(void* const* d_in, const int* in_sizes, int n_in,
                              void* d_out, int out_size, void* d_ws, size_t ws_size,
                              hipStream_t stream)
{
    const float* x    = (const float*)d_in[0];
    const float* loss = (const float*)d_in[1];
    // d_in[2] = sub_path (int scalar) -> single path, ignored
    const float* w1   = (const float*)d_in[3];
    const float* w2   = (const float*)d_in[4];
    const float* bg1  = (const float*)d_in[5];
    const float* bb1  = (const float*)d_in[6];
    const float* bg2  = (const float*)d_in[7];
    const float* bb2  = (const float*)d_in[8];
    const float* b11  = (const float*)d_in[9];
    const float* b12  = (const float*)d_in[10];
    const float* b13  = (const float*)d_in[11];
    const float* b21  = (const float*)d_in[12];
    const float* b22  = (const float*)d_in[13];
    const float* b23  = (const float*)d_in[14];
    const float* p1   = (const float*)d_in[15];
    const float* p2   = (const float*)d_in[16];
    float* out = (float*)d_out;

    char* ws = (char*)d_ws;
    uint32_t* wmask1 = (uint32_t*)(ws + 0);        // 576*4
    float* alpha1f   = (float*)(ws + 4096);
    double* alpha2   = (double*)(ws + 8192);
    ull*   wpos2     = (ull*)(ws + 12288);
    ull*   wnz2      = (ull*)(ws + 16384);
    float* mu_f      = (float*)(ws + 20480);
    float* inv_f     = (float*)(ws + 24576);
    float* sA1       = (float*)(ws + 28672);
    float* sh1       = (float*)(ws + 32768);
    float* sA2       = (float*)(ws + 36864);
    float* sh2       = (float*)(ws + 40960);
    int*   partS1    = (int*)(ws + 65536);                   // 2048*16*4 = 128 KB
    int*   partQ1    = (int*)(ws + 65536 + 131072);          // 128 KB
    int*   partS2    = (int*)(ws + 65536 + 262144);          // 1024*64*4 = 256 KB
    int*   partQ2    = (int*)(ws + 65536 + 262144 + 262144); // 256 KB
    uint4*  packed1  = (uint4*)(ws + 1048576);               // 2 MB
    int8_t* conv1s   = (int8_t*)(ws + 1048576 + 2097152);    // 8 MB
    ulonglong2* packed = (ulonglong2*)(ws + 1048576 + 2097152 + 8388608); // 2 MB

    k0_prep<<<1, 576, 0, stream>>>(w1, w2, loss, out + NELEM,
                                   wmask1, alpha1f, wpos2, wnz2, alpha2);
    k1a_pack<<<NPIX / 256, 256, 0, stream>>>(x, b11, packed1);
    k1_conv1<<<dim3(64, 32), 256, 0, stream>>>((const uint32_t*)packed1, wmask1,
                                               conv1s, partS1, partQ1);
    f1_bn<<<1, 1024, 0, stream>>>(bg1, bb1, alpha1f, partS1, partQ1, mu_f, inv_f, sA1, sh1);
    k2b_pack<<<NPIX / 256, 256, 0, stream>>>(conv1s, x, alpha1f, mu_f, inv_f,
                                             bg1, bb1, b12, p1, b13, b21, packed);
    k3_stats2<<<K3BLK, 256, 0, stream>>>(packed, wpos2, wnz2, partS2, partQ2);
    f2_bn<<<1, 1024, 0, stream>>>(bg2, bb2, alpha2, partS2, partQ2, sA2, sh2);
    k4_out2<<<NELEM / 1024, 256, 0, stream>>>(packed, conv1s, x, sA1, sh1, b12, p1, b13,
                                              wpos2, wnz2, sA2, sh2, b22, p2, b23, out);
}

// Round 10
// 123.710 us; speedup vs baseline: 1.1790x; 1.1790x over previous
//
#include <hip/hip_runtime.h>
#include <hip/hip_bf16.h>
#include <stdint.h>

typedef unsigned long long ull;

#define B_   8
#define C_   64
#define H_   128
#define W_   128
#define HW_  (H_*W_)          // 16384
#define NPIX (B_*HW_)         // 131072
#define NELEM (B_*C_*HW_)     // 8388608
#define G1_  4
#define CPG_ 16
#define TAU_ 5e-5f            // zero-band half-width for act2 sign decision
#define K3BLK 1024
#define K1BLKS 512            // 64 tiles (2x32) * 8 batches

// ---------------- K1a: per-pixel ternary sign pack (x4 pixels) + fused prep --------
// packed1[p] = uint4, component g = (nz16<<16)|pos16 for channels g*16..g*16+15.
// Last block (blockIdx.x == NPIX/1024) does the weight prep instead.
__global__ __launch_bounds__(256) void k1a_pack(
    const float* __restrict__ x, const float* __restrict__ b11,
    uint4* __restrict__ packed1,
    const float* __restrict__ w1, const float* __restrict__ w2,
    const float* __restrict__ loss, float* __restrict__ loss_out,
    uint32_t* __restrict__ wP, uint32_t* __restrict__ wN, float* __restrict__ alpha1f,
    ull* __restrict__ wpos2, ull* __restrict__ wnz2, double* __restrict__ alpha2)
{
    int t = threadIdx.x;
    if (blockIdx.x == NPIX / 1024) {
        // ---- prep ----
        if (t == 0) loss_out[0] = loss[0];
        if (t < 64) {
            const float* wo = w1 + t * CPG_ * 9;
            double s = 0.0;
            for (int i = 0; i < CPG_ * 9; i++) s += fabs((double)wo[i]);
            alpha1f[t] = (float)(s / (double)(CPG_ * 9));
        }
        if (t < 64) {
            double s = 0.0; ull pos = 0ull, nz = 0ull;
            for (int i = 0; i < 64; i++) {
                float w = w2[t * 64 + i];
                s += fabs((double)w);
                if (w > 0.f) pos |= (1ull << i);
                if (w != 0.f) nz |= (1ull << i);
            }
            alpha2[t] = s / 64.0;
            wpos2[t] = pos; wnz2[t] = nz;
        }
        // paired weight masks: [g][oc][pair] over taps (2*pr, 2*pr+1), pr=4 -> tap8 only
        for (int e = t; e < G1_ * CPG_ * 5; e += 256) {
            int g = e / 80, r = e % 80, oc = r / 5, pr = r % 5;
            int o = g * CPG_ + oc;
            int t0 = 2 * pr, t1 = 2 * pr + 1;
            uint32_t p0 = 0, n0 = 0, p1 = 0, n1 = 0;
            for (int i = 0; i < CPG_; i++) {
                float wa = w1[(o * CPG_ + i) * 9 + t0];
                if (wa > 0.f) p0 |= (1u << i);
                if (wa != 0.f) n0 |= (1u << i);
                if (t1 < 9) {
                    float wb = w1[(o * CPG_ + i) * 9 + t1];
                    if (wb > 0.f) p1 |= (1u << i);
                    if (wb != 0.f) n1 |= (1u << i);
                }
            }
            wP[e] = p0 | (p1 << 16);
            wN[e] = n0 | (n1 << 16);
        }
        return;
    }
    // ---- main: pack 4 pixels/thread ----
    __shared__ float cB11[64];
    if (t < 64) cB11[t] = b11[t];
    __syncthreads();
    int p4 = (blockIdx.x * 256 + t) * 4;
    int b = p4 >> 14, hw = p4 & (HW_ - 1);
    const float* xb = x + (size_t)b * C_ * HW_ + hw;
    uint32_t mm[4][4] = {};
    #pragma unroll
    for (int c = 0; c < 64; c++) {
        float4 xv = *(const float4*)(xb + (size_t)c * HW_);
        float bc = cB11[c];
        int g = c >> 4, bit = c & 15;
        float vv[4] = {xv.x, xv.y, xv.z, xv.w};
        #pragma unroll
        for (int k = 0; k < 4; k++) {
            float v = __fadd_rn(vv[k], bc);
            uint32_t pos = (v > 0.f) ? 1u : 0u;
            uint32_t nz  = (v != 0.f) ? 1u : 0u;
            mm[k][g] |= (pos << bit) | (nz << (bit + 16));
        }
    }
    #pragma unroll
    for (int k = 0; k < 4; k++)
        packed1[p4 + k] = make_uint4(mm[k][0], mm[k][1], mm[k][2], mm[k][3]);
}

// ---------------- K1: 3x3 grouped ternary conv, tap-paired popcount ----------------
// Tile 64x4, all 4 groups per block; wave == row -> 64B-contiguous conv1s stores.
__global__ __launch_bounds__(256) void k1_conv1(
    const uint4* __restrict__ packed1,
    const uint32_t* __restrict__ wP, const uint32_t* __restrict__ wN,
    int8_t* __restrict__ conv1s,
    int* __restrict__ partS1, int* __restrict__ partQ1)
{
    const int b = blockIdx.y;
    const int x0 = (blockIdx.x & 1) * 64;
    const int y0 = (blockIdx.x >> 1) * 4;

    __shared__ uint32_t sP[4][6][66];     // [group][row][col]
    __shared__ uint32_t sWp[320], sWn[320];
    __shared__ int redS[4][64], redQ[4][64];

    int t = threadIdx.x;
    for (int i = t; i < 320; i += 256) { sWp[i] = wP[i]; sWn[i] = wN[i]; }  // FIX: full 320

    for (int i = t; i < 6 * 66; i += 256) {
        int row = i / 66, col = i % 66;
        int y = y0 - 1 + row, xc = x0 - 1 + col;
        uint4 m = make_uint4(0u, 0u, 0u, 0u);
        if (y >= 0 && y < H_ && xc >= 0 && xc < W_)
            m = packed1[(b << 14) + y * W_ + xc];
        sP[0][row][col] = m.x; sP[1][row][col] = m.y;
        sP[2][row][col] = m.z; sP[3][row][col] = m.w;
    }
    __syncthreads();

    int tyl = t >> 6, txl = t & 63;
    size_t pixbase = ((size_t)b * C_ << 14) + (size_t)(y0 + tyl) * W_ + x0 + txl;

    #pragma unroll
    for (int g = 0; g < 4; g++) {
        uint32_t a[9];
        #pragma unroll
        for (int dy = 0; dy < 3; dy++)
            #pragma unroll
            for (int dx = 0; dx < 3; dx++)
                a[dy * 3 + dx] = sP[g][tyl + dy][txl + dx];
        // re-pair activations: pos-pairs and nz-pairs (2 taps per word)
        uint32_t ap[5], an[5];
        #pragma unroll
        for (int pr = 0; pr < 4; pr++) {
            ap[pr] = (a[2 * pr] & 0xFFFFu) | (a[2 * pr + 1] << 16);
            an[pr] = (a[2 * pr] >> 16) | (a[2 * pr + 1] & 0xFFFF0000u);
        }
        ap[4] = a[8] & 0xFFFFu;
        an[4] = a[8] >> 16;

        #pragma unroll
        for (int oc = 0; oc < CPG_; oc++) {
            const int wbase = g * 80 + oc * 5;
            int pm = 0, pn = 0;
            #pragma unroll
            for (int pr = 0; pr < 5; pr++) {
                uint32_t nzb = sWn[wbase + pr] & an[pr];
                uint32_t mt  = (~(sWp[wbase + pr] ^ ap[pr])) & nzb;
                pm += __popc(mt);
                pn += __popc(nzb);
            }
            int s = 2 * pm - pn;
            int ch = g * CPG_ + oc;
            conv1s[pixbase + ((size_t)ch << 14)] = (int8_t)s;

            int sr = s, q = s * s;
            for (int off = 32; off > 0; off >>= 1) {
                sr += __shfl_down(sr, off, 64);
                q  += __shfl_down(q, off, 64);
            }
            if (txl == 0) { redS[tyl][ch] = sr; redQ[tyl][ch] = q; }
        }
    }
    __syncthreads();
    if (t < 64) {
        int bid = blockIdx.y * 64 + blockIdx.x;    // 0..511
        partS1[bid * 64 + t] = redS[0][t] + redS[1][t] + redS[2][t] + redS[3][t];
        partQ1[bid * 64 + t] = redQ[0][t] + redQ[1][t] + redQ[2][t] + redQ[3][t];
    }
}

// ---------------- F1: reduce partials -> BN1 channel constants ----------------------
__global__ __launch_bounds__(1024) void f1_bn(
    const float* __restrict__ gamma, const float* __restrict__ beta,
    const float* __restrict__ alpha1f,
    const int* __restrict__ partS1, const int* __restrict__ partQ1,
    float* __restrict__ mu_f, float* __restrict__ inv_f,
    float* __restrict__ sA, float* __restrict__ sh)
{
    __shared__ int rS[16][64];
    __shared__ long long rQ[16][64];
    int tid = threadIdx.x;
    int c = tid & 63, j = tid >> 6;      // 16 threads per channel
    int s = 0; long long q = 0;
    for (int i = j; i < K1BLKS; i += 16) {
        s += partS1[i * 64 + c];
        q += (long long)partQ1[i * 64 + c];
    }
    rS[j][c] = s; rQ[j][c] = q;
    __syncthreads();
    if (tid < 64) {
        int S = 0; long long Q = 0;
        #pragma unroll
        for (int k = 0; k < 16; k++) { S += rS[k][tid]; Q += rQ[k][tid]; }
        double n = (double)NPIX;
        double a = (double)alpha1f[tid];
        double sm = (double)S / n;
        double qm = (double)Q / n;
        double mu_d = a * sm;
        double var_d = a * a * (qm - sm * sm);
        double inv_d = 1.0 / sqrt(var_d + 1e-5);
        mu_f[tid] = (float)mu_d;
        inv_f[tid] = (float)inv_d;
        double scale = (double)gamma[tid] * inv_d;
        sA[tid] = (float)(scale * a);
        sh[tid] = (float)((double)beta[tid] - scale * mu_d);
    }
}

// ---------------- K2b: out1 recompute (ref op order, x4 pixels); ZERO-BAND pack -----
// act2 = sign(out1+b21) except |out1+b21| <= TAU_ -> 0 (cost <= sA2 ~ 0.156 < thr).
__global__ __launch_bounds__(256) void k2b_pack(
    const int8_t* __restrict__ conv1s, const float* __restrict__ x,
    const float* __restrict__ alpha1f,
    const float* __restrict__ mu_f, const float* __restrict__ inv_f,
    const float* __restrict__ g1, const float* __restrict__ be1,
    const float* __restrict__ b12, const float* __restrict__ p1, const float* __restrict__ b13,
    const float* __restrict__ b21,
    ulonglong2* __restrict__ packed)
{
    __shared__ float cAf[64], cMu[64], cInv[64], cG[64], cB[64],
                     cB12[64], cP1[64], cB13[64], cB21[64];
    int t = threadIdx.x;
    if (t < 64) {
        cAf[t] = alpha1f[t]; cMu[t] = mu_f[t]; cInv[t] = inv_f[t];
        cG[t] = g1[t]; cB[t] = be1[t];
        cB12[t] = b12[t]; cP1[t] = p1[t]; cB13[t] = b13[t]; cB21[t] = b21[t];
    }
    __syncthreads();

    int p4 = (blockIdx.x * 256 + t) * 4;
    int b = p4 >> 14, hw = p4 & (HW_ - 1);
    const int8_t* sbase = conv1s + (size_t)b * C_ * HW_ + hw;
    const float*  xbase = x      + (size_t)b * C_ * HW_ + hw;
    ull pos[4] = {0ull, 0ull, 0ull, 0ull};
    ull nz[4]  = {0ull, 0ull, 0ull, 0ull};
    #pragma unroll 4
    for (int c = 0; c < 64; c++) {
        char4  sv = *(const char4*)(sbase + ((size_t)c << 14));
        float4 xv = *(const float4*)(xbase + ((size_t)c << 14));
        float af = cAf[c], mu = cMu[c], iv = cInv[c], gg = cG[c], be = cB[c];
        float bb = cB12[c], pp = cP1[c], b3 = cB13[c], b2 = cB21[c];
        int si[4] = {sv.x, sv.y, sv.z, sv.w};
        float xx[4] = {xv.x, xv.y, xv.z, xv.w};
        #pragma unroll
        for (int k = 0; k < 4; k++) {
            float cf = __fmul_rn((float)si[k], af);     // = correctly-rounded fl(alpha*s)
            float v1 = __fsub_rn(cf, mu);
            float v2 = __fmul_rn(gg, v1);
            float v3 = __fmul_rn(v2, iv);
            float v4 = __fadd_rn(v3, be);
            float o  = __fadd_rn(v4, xx[k]);
            float tt = __fadd_rn(o, bb);
            float pr = (tt >= 0.f) ? tt : __fmul_rn(pp, tt);
            float o1 = __fadd_rn(pr, b3);
            float w  = __fadd_rn(o1, b2);
            if (w > TAU_)        pos[k] |= (1ull << c);
            if (fabsf(w) > TAU_) nz[k]  |= (1ull << c);
        }
    }
    #pragma unroll
    for (int k = 0; k < 4; k++)
        packed[p4 + k] = make_ulonglong2(pos[k], nz[k]);
}

// ---------------- K3: 1x1 ternary conv integer stats (high-occupancy partials) -----
__global__ __launch_bounds__(256) void k3_stats2(
    const ulonglong2* __restrict__ packed,
    const ull* __restrict__ wpos2, const ull* __restrict__ wnz2,
    int* __restrict__ partS2, int* __restrict__ partQ2)
{
    __shared__ int sS[4][64], sQ[4][64];
    int t = threadIdx.x;
    int lane = t & 63;
    int w = blockIdx.x * 4 + (t >> 6);
    ull wp = wpos2[lane], wn = wnz2[lane];
    int sacc = 0, qacc = 0;
    #pragma unroll 4
    for (int p = w; p < NPIX; p += 4 * K3BLK) {
        ulonglong2 pk = packed[p];
        ull nzb = wn & pk.y;
        ull match = (~(wp ^ pk.x)) & nzb;
        int s = 2 * __popcll(match) - __popcll(nzb);
        sacc += s;
        qacc += s * s;
    }
    sS[t >> 6][lane] = sacc; sQ[t >> 6][lane] = qacc;
    __syncthreads();
    if (t < 64) {
        partS2[blockIdx.x * 64 + t] = sS[0][t] + sS[1][t] + sS[2][t] + sS[3][t];
        partQ2[blockIdx.x * 64 + t] = sQ[0][t] + sQ[1][t] + sQ[2][t] + sQ[3][t];
    }
}

// ---------------- F2: reduce partials -> BN2 folded constants -----------------------
__global__ __launch_bounds__(1024) void f2_bn(
    const float* __restrict__ gamma, const float* __restrict__ beta,
    const double* __restrict__ alpha,
    const int* __restrict__ partS2, const int* __restrict__ partQ2,
    float* __restrict__ sA, float* __restrict__ sh)
{
    __shared__ int rS[16][64];
    __shared__ long long rQ[16][64];
    int tid = threadIdx.x;
    int c = tid & 63, j = tid >> 6;
    int s = 0; long long q = 0;
    for (int i = j; i < K3BLK; i += 16) {
        s += partS2[i * 64 + c];
        q += (long long)partQ2[i * 64 + c];
    }
    rS[j][c] = s; rQ[j][c] = q;
    __syncthreads();
    if (tid < 64) {
        int S = 0; long long Q = 0;
        #pragma unroll
        for (int k = 0; k < 16; k++) { S += rS[k][tid]; Q += rQ[k][tid]; }
        double n = (double)NPIX;
        double a = alpha[tid];
        double sm = (double)S / n;
        double qm = (double)Q / n;
        double var = a * a * (qm - sm * sm);
        double inv = 1.0 / sqrt(var + 1e-5);
        double scale = (double)gamma[tid] * inv;
        sA[tid] = (float)(scale * a);
        sh[tid] = (float)((double)beta[tid] - scale * a * sm);
    }
}

// ---------------- K4: out1 inline + 1x1 conv + BN2 + epilogue -> out ----------------
__global__ __launch_bounds__(256) void k4_out2(
    const ulonglong2* __restrict__ packed,
    const int8_t* __restrict__ conv1s, const float* __restrict__ x,
    const float* __restrict__ sA1, const float* __restrict__ sh1,
    const float* __restrict__ b12, const float* __restrict__ p1, const float* __restrict__ b13,
    const ull* __restrict__ wpos2, const ull* __restrict__ wnz2,
    const float* __restrict__ sA2, const float* __restrict__ sh2,
    const float* __restrict__ b22, const float* __restrict__ p2, const float* __restrict__ b23,
    float* __restrict__ out2)
{
    int i4 = (blockIdx.x * 256 + threadIdx.x) * 4;
    if (i4 >= NELEM) return;
    int c = (i4 >> 14) & 63;
    int b = i4 >> 20;
    int hw = i4 & (HW_ - 1);
    int p = b * HW_ + hw;
    ull wp = wpos2[c], wn = wnz2[c];
    float a1 = sA1[c], s1c = sh1[c], bb1 = b12[c], pp1 = p1[c], b31 = b13[c];
    float a2 = sA2[c], s2c = sh2[c], bb2 = b22[c], pp2 = p2[c], b32 = b23[c];
    char4 sv = *(const char4*)(conv1s + i4);
    float4 xv = *(const float4*)(x + i4);
    float ss[4] = {(float)sv.x, (float)sv.y, (float)sv.z, (float)sv.w};
    float xx[4] = {xv.x, xv.y, xv.z, xv.w};
    float r[4];
    #pragma unroll
    for (int k = 0; k < 4; k++) {
        float v = a1 * ss[k] + s1c + xx[k];
        float t1 = v + bb1;
        float pr1 = t1 >= 0.f ? t1 : pp1 * t1;
        float o1 = pr1 + b31;
        ulonglong2 pk = packed[p + k];
        ull nzb = wn & pk.y;
        ull match = (~(wp ^ pk.x)) & nzb;
        int s = 2 * __popcll(match) - __popcll(nzb);
        float v2 = a2 * (float)s + s2c + o1;
        float t2 = v2 + bb2;
        float pr2 = t2 >= 0.f ? t2 : pp2 * t2;
        r[k] = pr2 + b32;
    }
    *(float4*)(out2 + i4) = make_float4(r[0], r[1], r[2], r[3]);
}

// ---------------- launch ----------------
extern "C" void kernel_launch(void* const* d_in, const int* in_sizes, int n_in,
                              void* d_out, int out_size, void* d_ws, size_t ws_size,
                              hipStream_t stream)
{
    const float* x    = (const float*)d_in[0];
    const float* loss = (const float*)d_in[1];
    // d_in[2] = sub_path (int scalar) -> single path, ignored
    const float* w1   = (const float*)d_in[3];
    const float* w2   = (const float*)d_in[4];
    const float* bg1  = (const float*)d_in[5];
    const float* bb1  = (const float*)d_in[6];
    const float* bg2  = (const float*)d_in[7];
    const float* bb2  = (const float*)d_in[8];
    const float* b11  = (const float*)d_in[9];
    const float* b12  = (const float*)d_in[10];
    const float* b13  = (const float*)d_in[11];
    const float* b21  = (const float*)d_in[12];
    const float* b22  = (const float*)d_in[13];
    const float* b23  = (const float*)d_in[14];
    const float* p1   = (const float*)d_in[15];
    const float* p2   = (const float*)d_in[16];
    float* out = (float*)d_out;

    char* ws = (char*)d_ws;
    uint32_t* wP     = (uint32_t*)(ws + 0);          // 320 words
    uint32_t* wN     = (uint32_t*)(ws + 4096);       // 320 words
    float* alpha1f   = (float*)(ws + 8192);
    double* alpha2   = (double*)(ws + 12288);
    ull*   wpos2     = (ull*)(ws + 16384);
    ull*   wnz2      = (ull*)(ws + 20480);
    float* mu_f      = (float*)(ws + 24576);
    float* inv_f     = (float*)(ws + 28672);
    float* sA1       = (float*)(ws + 32768);
    float* sh1       = (float*)(ws + 36864);
    float* sA2       = (float*)(ws + 40960);
    float* sh2       = (float*)(ws + 45056);
    int*   partS1    = (int*)(ws + 65536);                    // 512*64*4 = 128 KB
    int*   partQ1    = (int*)(ws + 65536 + 131072);           // 128 KB
    int*   partS2    = (int*)(ws + 393216);                   // 1024*64*4 = 256 KB
    int*   partQ2    = (int*)(ws + 393216 + 262144);          // 256 KB
    uint4*  packed1  = (uint4*)(ws + 1048576);                // 2 MB
    int8_t* conv1s   = (int8_t*)(ws + 1048576 + 2097152);     // 8 MB
    ulonglong2* packed = (ulonglong2*)(ws + 1048576 + 2097152 + 8388608); // 2 MB

    k1a_pack<<<NPIX / 1024 + 1, 256, 0, stream>>>(x, b11, packed1,
                                                  w1, w2, loss, out + NELEM,
                                                  wP, wN, alpha1f, wpos2, wnz2, alpha2);
    k1_conv1<<<dim3(64, 8), 256, 0, stream>>>(packed1, wP, wN, conv1s, partS1, partQ1);
    f1_bn<<<1, 1024, 0, stream>>>(bg1, bb1, alpha1f, partS1, partQ1, mu_f, inv_f, sA1, sh1);
    k2b_pack<<<NPIX / 1024, 256, 0, stream>>>(conv1s, x, alpha1f, mu_f, inv_f,
                                              bg1, bb1, b12, p1, b13, b21, packed);
    k3_stats2<<<K3BLK, 256, 0, stream>>>(packed, wpos2, wnz2, partS2, partQ2);
    f2_bn<<<1, 1024, 0, stream>>>(bg2, bb2, alpha2, partS2, partQ2, sA2, sh2);
    k4_out2<<<NELEM / 1024, 256, 0, stream>>>(packed, conv1s, x, sA1, sh1, b12, p1, b13,
                                              wpos2, wnz2, sA2, sh2, b22, p2, b23, out);
}